// Round 1
// baseline (259.570 us; speedup 1.0000x reference)
//
#include <hip/hip_runtime.h>
#include <math.h>

// ---------------------------------------------------------------------------
// HematoxylinFFTModel: h = max(hed_w . (log(clamp(x,1e-6,1))/log(1e-6)), 0)
// F = fftshift(fft2(h, norm='forward')); lm = log1p(|F|)
// out = A*lm + B with A,B from per-image min/max + mean/var (instance norm)
// ---------------------------------------------------------------------------

__device__ __forceinline__ int rev9(int i) { return (int)(__brev((unsigned)i) >> 23); }

// Pass 1: hematoxylin + 512-pt row FFT. One block per (image,row).
__global__ __launch_bounds__(256) void k_rowfft(const float* __restrict__ x,
                                                float2* __restrict__ F,
                                                float w0, float w1, float w2) {
    const int b = blockIdx.x >> 9;
    const int row = blockIdx.x & 511;
    __shared__ float2 X[512];
    const float* xr = x + (size_t)b * 786432 + ((size_t)row << 9);
    for (int i = threadIdx.x; i < 512; i += 256) {
        float r  = xr[i];
        float g  = xr[262144 + i];
        float bl = xr[524288 + i];
        r  = fminf(fmaxf(r,  1e-6f), 1.0f);
        g  = fminf(fmaxf(g,  1e-6f), 1.0f);
        bl = fminf(fmaxf(bl, 1e-6f), 1.0f);
        // w* already include 1/log(1e-6) and the forward-FFT 1/(512*512)
        float h = fmaxf(w0 * logf(r) + w1 * logf(g) + w2 * logf(bl), 0.0f);
        X[rev9(i)] = make_float2(h, 0.0f);
    }
    __syncthreads();
    #pragma unroll
    for (int s = 0; s < 9; ++s) {
        const int half = 1 << s;
        const int j = threadIdx.x;                 // 256 butterflies, 1/thread
        const int pos = j & (half - 1);
        const int idx1 = ((j >> s) << (s + 1)) | pos;
        const int idx2 = idx1 + half;
        float sn, cs;
        __sincosf(-3.14159265358979323846f * (float)pos / (float)half, &sn, &cs);
        float2 a  = X[idx1];
        float2 bb = X[idx2];
        float tr = bb.x * cs - bb.y * sn;
        float ti = bb.x * sn + bb.y * cs;
        X[idx1] = make_float2(a.x + tr, a.y + ti);
        X[idx2] = make_float2(a.x - tr, a.y - ti);
        __syncthreads();
    }
    float2* Fr = F + ((size_t)b << 18) + ((size_t)row << 9);
    for (int i = threadIdx.x; i < 512; i += 256) Fr[i] = X[i];
}

// Pass 2: column FFTs (8 columns per block), magnitude+log1p+fftshift write
// into logmag (=d_out), and per-block {min,max,sum,sumsq} partials.
__global__ __launch_bounds__(256) void k_colfft(const float2* __restrict__ F,
                                                float* __restrict__ logmag,
                                                float4* __restrict__ partials) {
    const int b  = blockIdx.x >> 6;
    const int cg = blockIdx.x & 63;
    const int c0 = cg << 3;
    __shared__ float2 X[8][513];   // pad 512->513 breaks bank aliasing
    const float2* Fb = F + ((size_t)b << 18);
    for (int i = threadIdx.x; i < 4096; i += 256) {
        int y = i >> 3, c = i & 7;
        X[c][rev9(y)] = Fb[(y << 9) + c0 + c];
    }
    __syncthreads();
    const int c  = threadIdx.x & 7;
    const int j0 = threadIdx.x >> 3;               // 0..31, 8 butterflies each
    for (int s = 0; s < 9; ++s) {
        const int half = 1 << s;
        #pragma unroll
        for (int k = 0; k < 8; ++k) {
            const int j = j0 + (k << 5);
            const int pos = j & (half - 1);
            const int idx1 = ((j >> s) << (s + 1)) | pos;
            const int idx2 = idx1 + half;
            float sn, cs;
            __sincosf(-3.14159265358979323846f * (float)pos / (float)half, &sn, &cs);
            float2 a  = X[c][idx1];
            float2 bb = X[c][idx2];
            float tr = bb.x * cs - bb.y * sn;
            float ti = bb.x * sn + bb.y * cs;
            X[c][idx1] = make_float2(a.x + tr, a.y + ti);
            X[c][idx2] = make_float2(a.x - tr, a.y - ti);
        }
        __syncthreads();
    }
    float mn = 1e30f, mx = -1e30f, s1 = 0.0f, s2 = 0.0f;
    float* lm_b = logmag + ((size_t)b << 18);
    const int colbase = (c0 + 256) & 511;          // no wrap within 8-col group
    for (int i = threadIdx.x; i < 4096; i += 256) {
        int y = i >> 3, cc = i & 7;
        float2 v = X[cc][y];
        float mag = sqrtf(v.x * v.x + v.y * v.y);
        float lv = log1pf(mag);
        int ro = (y + 256) & 511;
        lm_b[(ro << 9) + colbase + cc] = lv;
        mn = fminf(mn, lv);
        mx = fmaxf(mx, lv);
        s1 += lv;
        s2 += lv * lv;
    }
    #pragma unroll
    for (int off = 32; off > 0; off >>= 1) {
        mn = fminf(mn, __shfl_down(mn, off, 64));
        mx = fmaxf(mx, __shfl_down(mx, off, 64));
        s1 += __shfl_down(s1, off, 64);
        s2 += __shfl_down(s2, off, 64);
    }
    __shared__ float4 wred[4];
    const int wave = threadIdx.x >> 6;
    const int lane = threadIdx.x & 63;
    if (lane == 0) wred[wave] = make_float4(mn, mx, s1, s2);
    __syncthreads();
    if (threadIdx.x == 0) {
        float4 r = wred[0];
        #pragma unroll
        for (int wv = 1; wv < 4; ++wv) {
            float4 q = wred[wv];
            r.x = fminf(r.x, q.x);
            r.y = fmaxf(r.y, q.y);
            r.z += q.z;
            r.w += q.w;
        }
        partials[blockIdx.x] = r;
    }
}

// Pass 3: fold 64 partials/image into per-image affine (A,B).
__global__ __launch_bounds__(64) void k_coeff(const float4* __restrict__ partials,
                                              const float* __restrict__ gamma,
                                              const float* __restrict__ beta,
                                              float2* __restrict__ coeff) {
    const int b = blockIdx.x;
    float4 r = partials[(b << 6) + threadIdx.x];
    float mn = r.x, mx = r.y, s1 = r.z, s2 = r.w;
    #pragma unroll
    for (int off = 32; off > 0; off >>= 1) {
        mn = fminf(mn, __shfl_down(mn, off, 64));
        mx = fmaxf(mx, __shfl_down(mx, off, 64));
        s1 += __shfl_down(s1, off, 64);
        s2 += __shfl_down(s2, off, 64);
    }
    if (threadIdx.x == 0) {
        const float N = 262144.0f;
        float mean = s1 / N;
        float var = fmaxf(s2 / N - mean * mean, 0.0f);
        float rng = mx - mn;
        float g = gamma[0], bt = beta[0];
        float A, B;
        if (rng > 0.0f) {
            float inv = 1.0f / rng;
            float varn = var * inv * inv;           // var of min-max-normed
            float sc = 1.0f / sqrtf(varn + 1e-5f);
            A = g * sc * inv;
            B = bt - mean * A;
        } else {
            A = 0.0f;
            B = bt;
        }
        coeff[b] = make_float2(A, B);
    }
}

// Pass 4: in-place out = out*A + B, float4 vectorized.
__global__ __launch_bounds__(256) void k_norm(float* __restrict__ out,
                                              const float2* __restrict__ coeff) {
    const int idx = blockIdx.x * 256 + threadIdx.x;   // 16777216/4 float4s
    const int bimg = idx >> 16;                        // 65536 float4 / image
    float2 ab = coeff[bimg];
    float4 v = reinterpret_cast<float4*>(out)[idx];
    v.x = v.x * ab.x + ab.y;
    v.y = v.y * ab.x + ab.y;
    v.z = v.z * ab.x + ab.y;
    v.w = v.w * ab.x + ab.y;
    reinterpret_cast<float4*>(out)[idx] = v;
}

extern "C" void kernel_launch(void* const* d_in, const int* in_sizes, int n_in,
                              void* d_out, int out_size, void* d_ws, size_t ws_size,
                              hipStream_t stream) {
    const float* x     = (const float*)d_in[0];
    const float* gamma = (const float*)d_in[1];
    const float* beta  = (const float*)d_in[2];
    float* out = (float*)d_out;

    // workspace layout: F (128 MB) | partials (64 KB) | coeff (512 B)
    float2* F = (float2*)d_ws;
    float4* partials = (float4*)((char*)d_ws + ((size_t)128 << 20));
    float2* coeff    = (float2*)((char*)d_ws + ((size_t)128 << 20) + 4096 * sizeof(float4));

    // hed_from_rgb[:,0] = column 0 of inv(rgb_from_hed), computed in double
    const double M00=0.65, M01=0.70, M02=0.29;
    const double M10=0.07, M11=0.99, M12=0.11;
    const double M20=0.27, M21=0.57, M22=0.78;
    const double det = M00*(M11*M22 - M12*M21)
                     - M01*(M10*M22 - M12*M20)
                     + M02*(M10*M21 - M11*M20);
    const float hw0 = (float)( (M11*M22 - M12*M21) / det);
    const float hw1 = (float)(-(M10*M22 - M12*M20) / det);
    const float hw2 = (float)( (M10*M21 - M11*M20) / det);
    // fold 1/log(1e-6) (negative) and forward-FFT 1/(512*512) (positive, OK
    // to hoist past the max(.,0) since positive) into the weights
    const float invLA = (float)(1.0 / log(1e-6));
    const float sN = 1.0f / (512.0f * 512.0f);
    const float w0 = hw0 * invLA * sN;
    const float w1 = hw1 * invLA * sN;
    const float w2 = hw2 * invLA * sN;

    k_rowfft<<<64 * 512, 256, 0, stream>>>(x, F, w0, w1, w2);
    k_colfft<<<64 * 64, 256, 0, stream>>>(F, out, partials);
    k_coeff<<<64, 64, 0, stream>>>(partials, gamma, beta, coeff);
    k_norm<<<16384, 256, 0, stream>>>(out, coeff);
}

// Round 2
// 177.003 us; speedup vs baseline: 1.4665x; 1.4665x over previous
//
#include <hip/hip_runtime.h>
#include <math.h>

// ---------------------------------------------------------------------------
// HematoxylinFFTModel: h = max(hed_w . (log(clamp(x,1e-6,1))/log(1e-6)), 0)
// F = fftshift(fft2(h, norm='forward')); lm = log1p(|F|)
// out = A*lm + B with A,B from per-image min/max + mean/var (instance norm)
//
// Round 2: twiddle LDS table (kills per-butterfly sincos), Hermitian symmetry
// (row-pair packing halves row FFTs; only columns 0..256 column-FFT'd, rest
// mirrored), bank-conflict swizzle (pad i+(i>>4), colfft column stride 546).
// ---------------------------------------------------------------------------

#define PI_F 3.14159265358979323846f
#define SW(i) ((i) + ((i) >> 4))

__device__ __forceinline__ int rev9(int i) { return (int)(__brev((unsigned)i) >> 23); }

// Pass 1: hematoxylin + packed row-pair FFT. One block per (image, row-pair).
// z = h[2q] + i*h[2q+1]; after FFT, unpack Hermitian halves, store cols 0..256.
__global__ __launch_bounds__(256) void k_rowfft(const float* __restrict__ x,
                                                float2* __restrict__ F,
                                                float w0, float w1, float w2) {
    const int b = blockIdx.x >> 8;
    const int q = blockIdx.x & 255;          // rows 2q, 2q+1
    __shared__ float2 X[544];                // 512 + pad(i>>4)
    __shared__ float2 TW[256];               // exp(-i*pi*t/256)
    const int tid = threadIdx.x;
    {
        float sn, cs;
        __sincosf(-PI_F * (float)tid * (1.0f / 256.0f), &sn, &cs);
        TW[tid] = make_float2(cs, sn);
    }
    const float* xb = x + (size_t)b * 786432;
    const int base0 = (q << 10);             // row 2q start (2q*512)
    {
        const int i = tid << 1;              // two adjacent cols per thread
        float2 r0 = *(const float2*)(xb + base0 + i);
        float2 g0 = *(const float2*)(xb + 262144 + base0 + i);
        float2 b0 = *(const float2*)(xb + 524288 + base0 + i);
        float2 r1 = *(const float2*)(xb + base0 + 512 + i);
        float2 g1 = *(const float2*)(xb + 262144 + base0 + 512 + i);
        float2 b1 = *(const float2*)(xb + 524288 + base0 + 512 + i);
        #pragma unroll
        for (int k = 0; k < 2; ++k) {
            float rr0 = k ? r0.y : r0.x, gg0 = k ? g0.y : g0.x, bb0 = k ? b0.y : b0.x;
            float rr1 = k ? r1.y : r1.x, gg1 = k ? g1.y : g1.x, bb1 = k ? b1.y : b1.x;
            rr0 = fminf(fmaxf(rr0, 1e-6f), 1.0f);
            gg0 = fminf(fmaxf(gg0, 1e-6f), 1.0f);
            bb0 = fminf(fmaxf(bb0, 1e-6f), 1.0f);
            rr1 = fminf(fmaxf(rr1, 1e-6f), 1.0f);
            gg1 = fminf(fmaxf(gg1, 1e-6f), 1.0f);
            bb1 = fminf(fmaxf(bb1, 1e-6f), 1.0f);
            float h0 = fmaxf(w0 * logf(rr0) + w1 * logf(gg0) + w2 * logf(bb0), 0.0f);
            float h1 = fmaxf(w0 * logf(rr1) + w1 * logf(gg1) + w2 * logf(bb1), 0.0f);
            int d = rev9(i + k);
            X[SW(d)] = make_float2(h0, h1);
        }
    }
    __syncthreads();
    #pragma unroll
    for (int s = 0; s < 9; ++s) {
        const int half = 1 << s;
        const int j = tid;                   // 256 butterflies, 1/thread
        const int pos = j & (half - 1);
        const int i1 = ((j >> s) << (s + 1)) | pos;
        const int i2 = i1 + half;
        float2 w = TW[pos << (8 - s)];
        float2 a  = X[SW(i1)];
        float2 bb = X[SW(i2)];
        float tr = bb.x * w.x - bb.y * w.y;
        float ti = bb.x * w.y + bb.y * w.x;
        X[SW(i1)] = make_float2(a.x + tr, a.y + ti);
        X[SW(i2)] = make_float2(a.x - tr, a.y - ti);
        __syncthreads();
    }
    // unpack: F0[k] = 0.5(Z[k]+conj(Z[-k])), F1[k] = -0.5i(Z[k]-conj(Z[-k]))
    float2* Fb = F + ((size_t)b << 18);
    const int r0 = (q << 1), r1 = r0 + 1;
    {
        const int k = tid;
        const int m = (512 - k) & 511;
        float2 zk = X[SW(k)];
        float2 zm = X[SW(m)];
        float2 f0 = make_float2(0.5f * (zk.x + zm.x), 0.5f * (zk.y - zm.y));
        float2 f1 = make_float2(0.5f * (zk.y + zm.y), -0.5f * (zk.x - zm.x));
        Fb[(r0 << 9) + k] = f0;
        Fb[(r1 << 9) + k] = f1;
        if (tid == 0) {
            float2 z = X[SW(256)];
            Fb[(r0 << 9) + 256] = make_float2(z.x, 0.0f);
            Fb[(r1 << 9) + 256] = make_float2(z.y, 0.0f);
        }
    }
}

// Pass 2: column FFTs for u=0..256 (33 groups of 8), magnitude+log1p+fftshift
// write with Hermitian mirror to column 512-u, per-block stats partials.
#define CSTRIDE 546
__global__ __launch_bounds__(256) void k_colfft(const float2* __restrict__ F,
                                                float* __restrict__ logmag,
                                                float4* __restrict__ partials) {
    const int b = blockIdx.x / 33;
    const int g = blockIdx.x % 33;
    const int u0 = g << 3;
    __shared__ float2 X[8 * CSTRIDE];
    __shared__ float2 TW[256];
    __shared__ float4 wred[4];
    const int tid = threadIdx.x;
    {
        float sn, cs;
        __sincosf(-PI_F * (float)tid * (1.0f / 256.0f), &sn, &cs);
        TW[tid] = make_float2(cs, sn);
    }
    const float2* Fb = F + ((size_t)b << 18);
    for (int i = tid; i < 4096; i += 256) {
        int y = i >> 3, c = i & 7;
        int u = u0 + c;
        float2 v = (u <= 256) ? Fb[(y << 9) + u] : make_float2(0.0f, 0.0f);
        int d = rev9(y);
        X[c * CSTRIDE + SW(d)] = v;
    }
    __syncthreads();
    // one column per half-wave: c = tid>>5, 8 butterflies per thread
    {
        const int c = tid >> 5;
        const int j0 = tid & 31;
        float2* Xc = X + c * CSTRIDE;
        for (int s = 0; s < 9; ++s) {
            const int half = 1 << s;
            #pragma unroll
            for (int k = 0; k < 8; ++k) {
                const int j = j0 + (k << 5);
                const int pos = j & (half - 1);
                const int i1 = ((j >> s) << (s + 1)) | pos;
                const int i2 = i1 + half;
                float2 w = TW[pos << (8 - s)];
                float2 a  = Xc[SW(i1)];
                float2 bb = Xc[SW(i2)];
                float tr = bb.x * w.x - bb.y * w.y;
                float ti = bb.x * w.y + bb.y * w.x;
                Xc[SW(i1)] = make_float2(a.x + tr, a.y + ti);
                Xc[SW(i2)] = make_float2(a.x - tr, a.y - ti);
            }
            __syncthreads();
        }
    }
    float mn = 1e30f, mx = -1e30f, s1 = 0.0f, s2 = 0.0f;
    float* lm_b = logmag + ((size_t)b << 18);
    for (int i = tid; i < 4096; i += 256) {
        int y = i >> 3, cc = i & 7;
        int u = u0 + cc;
        if (u > 256) continue;
        float2 v = X[cc * CSTRIDE + SW(y)];
        float lv = log1pf(sqrtf(v.x * v.x + v.y * v.y));
        int ro = (y + 256) & 511;
        int co = (u + 256) & 511;
        lm_b[(ro << 9) + co] = lv;
        mn = fminf(mn, lv);
        mx = fmaxf(mx, lv);
        if (u == 0 || u == 256) {
            s1 += lv;
            s2 += lv * lv;
        } else {                             // mirror into column 512-u
            int rom = (256 - y) & 511;
            int com = 256 - u;
            lm_b[(rom << 9) + com] = lv;
            s1 += 2.0f * lv;
            s2 += 2.0f * lv * lv;
        }
    }
    #pragma unroll
    for (int off = 32; off > 0; off >>= 1) {
        mn = fminf(mn, __shfl_down(mn, off, 64));
        mx = fmaxf(mx, __shfl_down(mx, off, 64));
        s1 += __shfl_down(s1, off, 64);
        s2 += __shfl_down(s2, off, 64);
    }
    const int wave = tid >> 6;
    const int lane = tid & 63;
    if (lane == 0) wred[wave] = make_float4(mn, mx, s1, s2);
    __syncthreads();
    if (tid == 0) {
        float4 r = wred[0];
        #pragma unroll
        for (int wv = 1; wv < 4; ++wv) {
            float4 q2 = wred[wv];
            r.x = fminf(r.x, q2.x);
            r.y = fmaxf(r.y, q2.y);
            r.z += q2.z;
            r.w += q2.w;
        }
        partials[blockIdx.x] = r;
    }
}

// Pass 3: fold 33 partials/image into per-image affine (A,B).
__global__ __launch_bounds__(64) void k_coeff(const float4* __restrict__ partials,
                                              const float* __restrict__ gamma,
                                              const float* __restrict__ beta,
                                              float2* __restrict__ coeff) {
    const int b = blockIdx.x;
    float mn = 1e30f, mx = -1e30f, s1 = 0.0f, s2 = 0.0f;
    if (threadIdx.x < 33) {
        float4 r = partials[b * 33 + threadIdx.x];
        mn = r.x; mx = r.y; s1 = r.z; s2 = r.w;
    }
    #pragma unroll
    for (int off = 32; off > 0; off >>= 1) {
        mn = fminf(mn, __shfl_down(mn, off, 64));
        mx = fmaxf(mx, __shfl_down(mx, off, 64));
        s1 += __shfl_down(s1, off, 64);
        s2 += __shfl_down(s2, off, 64);
    }
    if (threadIdx.x == 0) {
        const float N = 262144.0f;
        float mean = s1 / N;
        float var = fmaxf(s2 / N - mean * mean, 0.0f);
        float rng = mx - mn;
        float g = gamma[0], bt = beta[0];
        float A, B;
        if (rng > 0.0f) {
            float inv = 1.0f / rng;
            float varn = var * inv * inv;
            float sc = 1.0f / sqrtf(varn + 1e-5f);
            A = g * sc * inv;
            B = bt - mean * A;
        } else {
            A = 0.0f;
            B = bt;
        }
        coeff[b] = make_float2(A, B);
    }
}

// Pass 4: in-place out = out*A + B, float4 vectorized.
__global__ __launch_bounds__(256) void k_norm(float* __restrict__ out,
                                              const float2* __restrict__ coeff) {
    const int idx = blockIdx.x * 256 + threadIdx.x;
    const int bimg = idx >> 16;
    float2 ab = coeff[bimg];
    float4 v = reinterpret_cast<float4*>(out)[idx];
    v.x = v.x * ab.x + ab.y;
    v.y = v.y * ab.x + ab.y;
    v.z = v.z * ab.x + ab.y;
    v.w = v.w * ab.x + ab.y;
    reinterpret_cast<float4*>(out)[idx] = v;
}

extern "C" void kernel_launch(void* const* d_in, const int* in_sizes, int n_in,
                              void* d_out, int out_size, void* d_ws, size_t ws_size,
                              hipStream_t stream) {
    const float* x     = (const float*)d_in[0];
    const float* gamma = (const float*)d_in[1];
    const float* beta  = (const float*)d_in[2];
    float* out = (float*)d_out;

    // workspace: F (128 MB, cols 0..256 live) | partials (33.8 KB) | coeff
    float2* F = (float2*)d_ws;
    float4* partials = (float4*)((char*)d_ws + ((size_t)128 << 20));
    float2* coeff    = (float2*)((char*)d_ws + ((size_t)128 << 20) + 64 * 33 * sizeof(float4));

    const double M00=0.65, M01=0.70, M02=0.29;
    const double M10=0.07, M11=0.99, M12=0.11;
    const double M20=0.27, M21=0.57, M22=0.78;
    const double det = M00*(M11*M22 - M12*M21)
                     - M01*(M10*M22 - M12*M20)
                     + M02*(M10*M21 - M11*M20);
    const float hw0 = (float)( (M11*M22 - M12*M21) / det);
    const float hw1 = (float)(-(M10*M22 - M12*M20) / det);
    const float hw2 = (float)( (M10*M21 - M11*M20) / det);
    const float invLA = (float)(1.0 / log(1e-6));
    const float sN = 1.0f / (512.0f * 512.0f);
    const float w0 = hw0 * invLA * sN;
    const float w1 = hw1 * invLA * sN;
    const float w2 = hw2 * invLA * sN;

    k_rowfft<<<64 * 256, 256, 0, stream>>>(x, F, w0, w1, w2);
    k_colfft<<<64 * 33, 256, 0, stream>>>(F, out, partials);
    k_coeff<<<64, 64, 0, stream>>>(partials, gamma, beta, coeff);
    k_norm<<<16384, 256, 0, stream>>>(out, coeff);
}

// Round 3
// 151.077 us; speedup vs baseline: 1.7181x; 1.1716x over previous
//
#include <hip/hip_runtime.h>
#include <math.h>

// ---------------------------------------------------------------------------
// HematoxylinFFTModel round 3: radix-4 wave-synchronous FFTs.
//  - in-place DIT, stage order [radix2 @L=1, radix4 @L=2,8,32,128],
//    input in digit-reversed order drev9(n).
//  - rowfft: 1 wave per packed row-pair FFT (Hermitian 2-rows-in-1), 0 stage
//    barriers. colfft: 1 half-wave per column, 16 cols / block in 2 passes.
//  - hardware logs (__log2f): h rebased exactly; log1p -> log2(1+mag) is
//    legal since min-max + instance norm are scale-invariant in lv.
// ---------------------------------------------------------------------------

#define PI_F 3.14159265358979323846f
#define SW(i) ((i) + ((i) >> 4))
#define FSTR 544            // per-FFT LDS stride in float2 (SW(511)=542)
#define CSTR 548            // colfft per-column stride (bank offset 8/col)

// digit reversal for stage order [2,4,4,4,4]
__device__ __forceinline__ int drev9(int n) {
    return ((n & 3) << 7) | (((n >> 2) & 3) << 5) | (((n >> 4) & 3) << 3)
         | (((n >> 6) & 3) << 1) | (n >> 8);
}

__device__ __forceinline__ float2 cmul(float2 a, float2 w) {
    return make_float2(a.x * w.x - a.y * w.y, a.x * w.y + a.y * w.x);
}

// radix-2 butterfly on pair (2m, 2m+1), no twiddle (L=1 stage)
__device__ __forceinline__ void r2bf(float2* Xc, int m) {
    float2 a = Xc[SW(2 * m)], b = Xc[SW(2 * m + 1)];
    Xc[SW(2 * m)]     = make_float2(a.x + b.x, a.y + b.y);
    Xc[SW(2 * m + 1)] = make_float2(a.x - b.x, a.y - b.y);
}

// radix-4 DIT butterfly j at sub-length L=2^log2L (in-place, fwd: w=e^{-2pi i/512})
__device__ __forceinline__ void r4bf(float2* Xc, const float2* TW, int j, int log2L) {
    const int L = 1 << log2L;
    const int kk = j & (L - 1);
    const int base = ((j >> log2L) << (log2L + 2)) + kk;
    const int t1 = kk << (7 - log2L);          // kk * (512 / (4L))
    float2 a0 = Xc[SW(base)];
    float2 a1 = cmul(Xc[SW(base + L)],     TW[t1]);
    float2 a2 = cmul(Xc[SW(base + 2 * L)], TW[2 * t1]);
    float2 a3 = cmul(Xc[SW(base + 3 * L)], TW[3 * t1]);
    float2 t0 = make_float2(a0.x + a2.x, a0.y + a2.y);
    float2 u0 = make_float2(a0.x - a2.x, a0.y - a2.y);
    float2 t2 = make_float2(a1.x + a3.x, a1.y + a3.y);
    float2 u1 = make_float2(a1.x - a3.x, a1.y - a3.y);
    Xc[SW(base)]         = make_float2(t0.x + t2.x, t0.y + t2.y);
    Xc[SW(base + 2 * L)] = make_float2(t0.x - t2.x, t0.y - t2.y);
    Xc[SW(base + L)]     = make_float2(u0.x + u1.y, u0.y - u1.x);   // u0 - i*u1
    Xc[SW(base + 3 * L)] = make_float2(u0.x - u1.y, u0.y + u1.x);   // u0 + i*u1
}

__device__ __forceinline__ void hstore(float2* Xw, int c,
                                       float r0v, float g0v, float b0v,
                                       float r1v, float g1v, float b1v,
                                       float w0, float w1, float w2) {
    r0v = fminf(fmaxf(r0v, 1e-6f), 1.0f);
    g0v = fminf(fmaxf(g0v, 1e-6f), 1.0f);
    b0v = fminf(fmaxf(b0v, 1e-6f), 1.0f);
    r1v = fminf(fmaxf(r1v, 1e-6f), 1.0f);
    g1v = fminf(fmaxf(g1v, 1e-6f), 1.0f);
    b1v = fminf(fmaxf(b1v, 1e-6f), 1.0f);
    float h0 = fmaxf(w0 * __log2f(r0v) + w1 * __log2f(g0v) + w2 * __log2f(b0v), 0.0f);
    float h1 = fmaxf(w0 * __log2f(r1v) + w1 * __log2f(g1v) + w2 * __log2f(b1v), 0.0f);
    Xw[SW(drev9(c))] = make_float2(h0, h1);
}

// Pass 1: hematoxylin + packed row-pair FFT, 4 FFTs (8 rows) per block,
// one wave per FFT -> no stage barriers.
__global__ __launch_bounds__(256) void k_rowfft(const float* __restrict__ x,
                                                float2* __restrict__ F,
                                                float w0, float w1, float w2) {
    const int b = blockIdx.x >> 6;          // image
    const int p = blockIdx.x & 63;          // row octet
    __shared__ float2 X[4 * FSTR];
    __shared__ float2 TW[512];
    const int tid = threadIdx.x;
    {
        float sn, cs;
        __sincosf(-PI_F * (float)tid * (1.0f / 256.0f), &sn, &cs);
        TW[tid]       = make_float2(cs, sn);
        TW[tid + 256] = make_float2(-cs, -sn);
    }
    const int w = tid >> 6, lane = tid & 63;
    float2* Xw = X + w * FSTR;
    const float* xb = x + (size_t)b * 786432;
    const int r0 = (p << 3) + (w << 1);     // packed rows r0, r0+1

    #pragma unroll
    for (int q = 0; q < 2; ++q) {
        const int cb = (q << 8) + (lane << 2);
        float4 R0 = *(const float4*)(xb +          (r0 << 9) + cb);
        float4 G0 = *(const float4*)(xb + 262144 + (r0 << 9) + cb);
        float4 B0 = *(const float4*)(xb + 524288 + (r0 << 9) + cb);
        float4 R1 = *(const float4*)(xb +          ((r0 + 1) << 9) + cb);
        float4 G1 = *(const float4*)(xb + 262144 + ((r0 + 1) << 9) + cb);
        float4 B1 = *(const float4*)(xb + 524288 + ((r0 + 1) << 9) + cb);
        hstore(Xw, cb + 0, R0.x, G0.x, B0.x, R1.x, G1.x, B1.x, w0, w1, w2);
        hstore(Xw, cb + 1, R0.y, G0.y, B0.y, R1.y, G1.y, B1.y, w0, w1, w2);
        hstore(Xw, cb + 2, R0.z, G0.z, B0.z, R1.z, G1.z, B1.z, w0, w1, w2);
        hstore(Xw, cb + 3, R0.w, G0.w, B0.w, R1.w, G1.w, B1.w, w0, w1, w2);
    }
    __syncthreads();                        // TW visible (X is wave-local)

    #pragma unroll
    for (int t = 0; t < 4; ++t) r2bf(Xw, lane + (t << 6));
    __builtin_amdgcn_wave_barrier();
    #pragma unroll
    for (int lg = 1; lg <= 7; lg += 2) {    // L = 2, 8, 32, 128
        r4bf(Xw, TW, lane, lg);
        r4bf(Xw, TW, lane + 64, lg);
        __builtin_amdgcn_wave_barrier();
    }

    // Hermitian unpack: F0[k]=0.5(Z[k]+conj(Z[-k])), F1[k]=-0.5i(Z[k]-conj(Z[-k]))
    float2* Fb = F + ((size_t)b << 18);
    #pragma unroll
    for (int t = 0; t < 4; ++t) {
        int k = lane + (t << 6);
        int m = (512 - k) & 511;
        float2 zk = Xw[SW(k)];
        float2 zm = Xw[SW(m)];
        Fb[(r0 << 9) + k]       = make_float2(0.5f * (zk.x + zm.x),  0.5f * (zk.y - zm.y));
        Fb[((r0 + 1) << 9) + k] = make_float2(0.5f * (zk.y + zm.y), -0.5f * (zk.x - zm.x));
    }
    if (lane == 0) {
        float2 z = Xw[SW(256)];
        Fb[(r0 << 9) + 256]       = make_float2(z.x, 0.0f);
        Fb[((r0 + 1) << 9) + 256] = make_float2(z.y, 0.0f);
    }
}

// Pass 2: column FFTs, 16 columns per block in 2 passes of 8, one half-wave
// per column; magnitude+log2(1+.)+fftshift with Hermitian mirror; stats.
__global__ __launch_bounds__(256) void k_colfft(const float2* __restrict__ F,
                                                float* __restrict__ logmag,
                                                float4* __restrict__ partials) {
    const int b = blockIdx.x / 17;
    const int g = blockIdx.x % 17;
    __shared__ float2 X[8 * CSTR];
    __shared__ float2 TW[512];
    __shared__ float4 wred[4];
    const int tid = threadIdx.x;
    {
        float sn, cs;
        __sincosf(-PI_F * (float)tid * (1.0f / 256.0f), &sn, &cs);
        TW[tid]       = make_float2(cs, sn);
        TW[tid + 256] = make_float2(-cs, -sn);
    }
    const float2* Fb = F + ((size_t)b << 18);
    float* lm_b = logmag + ((size_t)b << 18);
    float mn = 1e30f, mx = -1e30f, s1 = 0.0f, s2 = 0.0f;

    for (int pass = 0; pass < 2; ++pass) {
        const int u0 = (g << 4) + (pass << 3);
        __syncthreads();                    // X free of previous-pass readers
        for (int i = tid; i < 4096; i += 256) {
            int y = i >> 3, c = i & 7;
            int u = u0 + c;
            float2 v = (u <= 256) ? Fb[(y << 9) + u] : make_float2(0.0f, 0.0f);
            X[c * CSTR + SW(drev9(y))] = v;
        }
        __syncthreads();
        {
            const int c = tid >> 5, j0 = tid & 31;
            float2* Xc = X + c * CSTR;
            #pragma unroll
            for (int t = 0; t < 8; ++t) r2bf(Xc, j0 + (t << 5));
            __builtin_amdgcn_wave_barrier();
            #pragma unroll
            for (int lg = 1; lg <= 7; lg += 2) {
                #pragma unroll
                for (int t = 0; t < 4; ++t) r4bf(Xc, TW, j0 + (t << 5), lg);
                __builtin_amdgcn_wave_barrier();
            }
        }
        __syncthreads();
        for (int i = tid; i < 4096; i += 256) {
            int y = i >> 3, c = i & 7;
            int u = u0 + c;
            if (u > 256) continue;
            float2 v = X[c * CSTR + SW(y)];
            float lv = __log2f(1.0f + sqrtf(v.x * v.x + v.y * v.y));
            int ro = (y + 256) & 511;
            int co = (u + 256) & 511;
            lm_b[(ro << 9) + co] = lv;
            mn = fminf(mn, lv);
            mx = fmaxf(mx, lv);
            if (u == 0 || u == 256) {
                s1 += lv; s2 += lv * lv;
            } else {
                int rom = (256 - y) & 511;
                lm_b[(rom << 9) + (256 - u)] = lv;
                s1 += 2.0f * lv; s2 += 2.0f * lv * lv;
            }
        }
    }

    #pragma unroll
    for (int off = 32; off > 0; off >>= 1) {
        mn = fminf(mn, __shfl_down(mn, off, 64));
        mx = fmaxf(mx, __shfl_down(mx, off, 64));
        s1 += __shfl_down(s1, off, 64);
        s2 += __shfl_down(s2, off, 64);
    }
    const int wave = tid >> 6, lane = tid & 63;
    if (lane == 0) wred[wave] = make_float4(mn, mx, s1, s2);
    __syncthreads();
    if (tid == 0) {
        float4 r = wred[0];
        #pragma unroll
        for (int wv = 1; wv < 4; ++wv) {
            float4 q2 = wred[wv];
            r.x = fminf(r.x, q2.x);
            r.y = fmaxf(r.y, q2.y);
            r.z += q2.z;
            r.w += q2.w;
        }
        partials[blockIdx.x] = r;
    }
}

// Pass 3: fold 17 partials/image into per-image affine (A,B).
__global__ __launch_bounds__(64) void k_coeff(const float4* __restrict__ partials,
                                              const float* __restrict__ gamma,
                                              const float* __restrict__ beta,
                                              float2* __restrict__ coeff) {
    const int b = blockIdx.x;
    float mn = 1e30f, mx = -1e30f, s1 = 0.0f, s2 = 0.0f;
    if (threadIdx.x < 17) {
        float4 r = partials[b * 17 + threadIdx.x];
        mn = r.x; mx = r.y; s1 = r.z; s2 = r.w;
    }
    #pragma unroll
    for (int off = 32; off > 0; off >>= 1) {
        mn = fminf(mn, __shfl_down(mn, off, 64));
        mx = fmaxf(mx, __shfl_down(mx, off, 64));
        s1 += __shfl_down(s1, off, 64);
        s2 += __shfl_down(s2, off, 64);
    }
    if (threadIdx.x == 0) {
        const float N = 262144.0f;
        float mean = s1 / N;
        float var = fmaxf(s2 / N - mean * mean, 0.0f);
        float rng = mx - mn;
        float g = gamma[0], bt = beta[0];
        float A, B;
        if (rng > 0.0f) {
            float inv = 1.0f / rng;
            float varn = var * inv * inv;
            float sc = 1.0f / sqrtf(varn + 1e-5f);
            A = g * sc * inv;
            B = bt - mean * A;
        } else {
            A = 0.0f;
            B = bt;
        }
        coeff[b] = make_float2(A, B);
    }
}

// Pass 4: in-place out = out*A + B, float4 vectorized.
__global__ __launch_bounds__(256) void k_norm(float* __restrict__ out,
                                              const float2* __restrict__ coeff) {
    const int idx = blockIdx.x * 256 + threadIdx.x;
    const int bimg = idx >> 16;
    float2 ab = coeff[bimg];
    float4 v = reinterpret_cast<float4*>(out)[idx];
    v.x = v.x * ab.x + ab.y;
    v.y = v.y * ab.x + ab.y;
    v.z = v.z * ab.x + ab.y;
    v.w = v.w * ab.x + ab.y;
    reinterpret_cast<float4*>(out)[idx] = v;
}

extern "C" void kernel_launch(void* const* d_in, const int* in_sizes, int n_in,
                              void* d_out, int out_size, void* d_ws, size_t ws_size,
                              hipStream_t stream) {
    const float* x     = (const float*)d_in[0];
    const float* gamma = (const float*)d_in[1];
    const float* beta  = (const float*)d_in[2];
    float* out = (float*)d_out;

    float2* F = (float2*)d_ws;
    float4* partials = (float4*)((char*)d_ws + ((size_t)128 << 20));
    float2* coeff    = (float2*)((char*)d_ws + ((size_t)128 << 20) + 64 * 17 * sizeof(float4));

    const double M00=0.65, M01=0.70, M02=0.29;
    const double M10=0.07, M11=0.99, M12=0.11;
    const double M20=0.27, M21=0.57, M22=0.78;
    const double det = M00*(M11*M22 - M12*M21)
                     - M01*(M10*M22 - M12*M20)
                     + M02*(M10*M21 - M11*M20);
    const float hw0 = (float)( (M11*M22 - M12*M21) / det);
    const float hw1 = (float)(-(M10*M22 - M12*M20) / det);
    const float hw2 = (float)( (M10*M21 - M11*M20) / det);
    // h = hw . log(rgb) / log(1e-6) == hw . log2(rgb) / log2(1e-6); fold 1/N
    const float invLA2 = (float)(log(2.0) / log(1e-6));
    const float sN = 1.0f / (512.0f * 512.0f);
    const float w0 = hw0 * invLA2 * sN;
    const float w1 = hw1 * invLA2 * sN;
    const float w2 = hw2 * invLA2 * sN;

    k_rowfft<<<64 * 64, 256, 0, stream>>>(x, F, w0, w1, w2);
    k_colfft<<<64 * 17, 256, 0, stream>>>(F, out, partials);
    k_coeff<<<64, 64, 0, stream>>>(partials, gamma, beta, coeff);
    k_norm<<<16384, 256, 0, stream>>>(out, coeff);
}